// Round 1
// baseline (311.464 us; speedup 1.0000x reference)
//
#include <hip/hip_runtime.h>
#include <cstdint>

#define GEPS 1e-6f

typedef __attribute__((ext_vector_type(8))) short bf16x8;
typedef __attribute__((ext_vector_type(4))) float f32x4;

__device__ __forceinline__ unsigned short f2bf(float f) {
  unsigned int u = __float_as_uint(f);
  u += 0x7fffu + ((u >> 16) & 1u);
  return (unsigned short)(u >> 16);
}

// Pack W1 [C=256][H=256] fp32 -> bf16 fragment-major for the B-operand of
// mfma_f32_16x16x32_bf16: frag (h_tile, kk) is 1 KB; within it lane l=q*16+tl
// holds B[k = kk*32 + q*8 + j][h = h_tile*16 + tl], j=0..7 contiguous.
__global__ void pack_w1(const float* __restrict__ W1, unsigned short* __restrict__ wt) {
  int k = blockIdx.x;    // 0..255 (C)
  int h = threadIdx.x;   // 0..255 (H)
  float v = W1[k * 256 + h];
  int h_tile = h >> 4, tl = h & 15, kk = k >> 5, q = (k >> 3) & 3, j = k & 7;
  wt[(((h_tile << 3) + kk) << 9) + (q << 7) + (tl << 3) + j] = f2bf(v);
}

__global__ __launch_bounds__(256) void gater_main(
    const float* __restrict__ x, const unsigned short* __restrict__ wt,
    const float* __restrict__ b1, const float* __restrict__ w2,
    const float* __restrict__ b2,
    float* __restrict__ y, float* __restrict__ scores, float* __restrict__ probs,
    float* __restrict__ bg_ws, float* __restrict__ sums)
{
  __shared__ short A_lds[64 * 264];     // 64 tokens x 256 K bf16, stride 264 (pad)
  __shared__ float sc_lds[4][64];
  __shared__ float p_lds[64];
  __shared__ float bg_lds[4][256];

  const int tid = threadIdx.x;
  const int tok0 = blockIdx.x * 64;     // flat token index (b*N + n)
  const int b = tok0 >> 12;             // N = 4096
  const int n0 = tok0 & 4095;
  const float* xblk = x + (size_t)tok0 * 256;

  // ---- stage x tile fp32 -> bf16 into LDS (contiguous 4 KB per iter) ----
  #pragma unroll
  for (int i = 0; i < 16; ++i) {
    int f = i * 256 + tid;              // float4 index within 64x256 tile
    int token = f >> 6;
    int k4 = (f & 63) << 2;
    const float4 v = *(const float4*)(xblk + (size_t)f * 4);
    unsigned int lo = (unsigned int)f2bf(v.x) | ((unsigned int)f2bf(v.y) << 16);
    unsigned int hi = (unsigned int)f2bf(v.z) | ((unsigned int)f2bf(v.w) << 16);
    *(uint2*)&A_lds[token * 264 + k4] = make_uint2(lo, hi);
  }
  __syncthreads();

  const int wave = tid >> 6, lane = tid & 63, tl = lane & 15, q = lane >> 4;

  f32x4 acc[4][4];
  #pragma unroll
  for (int mi = 0; mi < 4; ++mi)
    #pragma unroll
    for (int ni = 0; ni < 4; ++ni)
      acc[mi][ni] = (f32x4){0.f, 0.f, 0.f, 0.f};

  const bf16x8* wtv = (const bf16x8*)wt;
  #pragma unroll
  for (int kk = 0; kk < 8; ++kk) {
    bf16x8 a[4], bb[4];
    #pragma unroll
    for (int mi = 0; mi < 4; ++mi)
      a[mi] = *(const bf16x8*)&A_lds[(mi * 16 + tl) * 264 + kk * 32 + q * 8];
    #pragma unroll
    for (int ni = 0; ni < 4; ++ni)
      bb[ni] = wtv[((((wave << 2) + ni) << 3) + kk) * 64 + lane];
    #pragma unroll
    for (int mi = 0; mi < 4; ++mi)
      #pragma unroll
      for (int ni = 0; ni < 4; ++ni)
        acc[mi][ni] = __builtin_amdgcn_mfma_f32_16x16x32_bf16(a[mi], bb[ni], acc[mi][ni], 0, 0, 0);
  }

  // ---- epilogue: gelu(h + b1) . w2, reduce over this wave's 64 H cols ----
  float w2v[4], b1v[4];
  #pragma unroll
  for (int ni = 0; ni < 4; ++ni) {
    int h = wave * 64 + ni * 16 + tl;
    w2v[ni] = w2[h];
    b1v[ni] = b1[h];
  }
  #pragma unroll
  for (int mi = 0; mi < 4; ++mi) {
    #pragma unroll
    for (int r = 0; r < 4; ++r) {
      float s = 0.f;
      #pragma unroll
      for (int ni = 0; ni < 4; ++ni) {
        float hv = acc[mi][ni][r] + b1v[ni];
        float g = 0.5f * hv * (1.0f + erff(hv * 0.70710678118654752f));
        s += g * w2v[ni];
      }
      #pragma unroll
      for (int m = 1; m < 16; m <<= 1) s += __shfl_xor(s, m, 64);
      if (tl == 0) sc_lds[wave][mi * 16 + q * 4 + r] = s;
    }
  }
  __syncthreads();

  if (tid < 64) {
    float s = sc_lds[0][tid] + sc_lds[1][tid] + sc_lds[2][tid] + sc_lds[3][tid] + b2[0];
    float p = 1.0f / (1.0f + expf(-s));
    size_t g = (size_t)tok0 + tid;
    scores[g] = s;
    probs[g] = p;
    p_lds[tid] = p;
    float ent = -(p * logf(p + GEPS) + (1.0f - p) * logf(1.0f - p + GEPS));
    float sp = p, se = ent;
    #pragma unroll
    for (int m = 1; m < 64; m <<= 1) {
      sp += __shfl_xor(sp, m, 64);
      se += __shfl_xor(se, m, 64);
    }
    if (tid == 0) {
      atomicAdd(&sums[b * 2 + 0], sp);
      atomicAdd(&sums[b * 2 + 1], se);
    }
  }
  __syncthreads();

  // ---- y = x * p (L2-hot re-read of x) + bg partial accumulation ----
  float4 bg = make_float4(0.f, 0.f, 0.f, 0.f);
  #pragma unroll
  for (int i = 0; i < 16; ++i) {
    int f = i * 256 + tid;
    int token = f >> 6;
    float4 xv = *(const float4*)(xblk + (size_t)f * 4);
    float p = p_lds[token];
    float4 yv = make_float4(xv.x * p, xv.y * p, xv.z * p, xv.w * p);
    size_t row = (size_t)b * 4097 + (size_t)(n0 + token);
    *(float4*)(y + row * 256 + ((f & 63) << 2)) = yv;
    float bw = 1.0f - p;
    bg.x += xv.x * bw; bg.y += xv.y * bw; bg.z += xv.z * bw; bg.w += xv.w * bw;
  }
  *(float4*)&bg_lds[tid >> 6][(tid & 63) << 2] = bg;
  __syncthreads();
  {
    int c = tid;
    float v = bg_lds[0][c] + bg_lds[1][c] + bg_lds[2][c] + bg_lds[3][c];
    atomicAdd(&bg_ws[b * 256 + c], v);
  }
}

__global__ void finalize(const float* __restrict__ bg_ws, const float* __restrict__ sums,
                         const int* __restrict__ kp, float* __restrict__ y,
                         float* __restrict__ aux)
{
  int b = blockIdx.x, c = threadIdx.x;
  float sp = sums[b * 2 + 0];
  float denom = fmaxf(4096.0f - sp, GEPS);
  y[((size_t)b * 4097 + 4096) * 256 + c] = bg_ws[b * 256 + c] / denom;
  if (b == 0 && c == 0) {
    float t = (float)kp[0] / 4096.0f;
    float lr = 0.f, le = 0.f;
    for (int i = 0; i < 32; ++i) {
      float r = sums[i * 2 + 0] / 4096.0f;
      lr += (r - t) * (r - t);
      le += sums[i * 2 + 1];
    }
    aux[0] = lr / 32.0f + 0.01f * (le / (32.0f * 4096.0f));
  }
}

extern "C" void kernel_launch(void* const* d_in, const int* in_sizes, int n_in,
                              void* d_out, int out_size, void* d_ws, size_t ws_size,
                              hipStream_t stream) {
  const float* x  = (const float*)d_in[0];
  const float* W1 = (const float*)d_in[1];
  const float* b1 = (const float*)d_in[2];
  const float* w2 = (const float*)d_in[3];
  const float* b2 = (const float*)d_in[4];
  const int*   kp = (const int*)d_in[5];

  float* y = (float*)d_out;
  const size_t Y_ELEMS = (size_t)32 * 4097 * 256;   // 33,562,624
  float* aux    = y + Y_ELEMS;
  float* scores = aux + 1;
  float* probs  = scores + (size_t)32 * 4096;

  unsigned short* wt = (unsigned short*)d_ws;                 // 128 KB bf16 frag-major W1
  float* bg_ws = (float*)((char*)d_ws + 131072);              // 32x256 fp32
  float* sums  = bg_ws + 32 * 256;                            // 32 x {sum_p, sum_ent}

  hipMemsetAsync(bg_ws, 0, (32 * 256 + 64) * sizeof(float), stream);
  pack_w1<<<256, 256, 0, stream>>>(W1, wt);
  gater_main<<<2048, 256, 0, stream>>>(x, wt, b1, w2, b2, y, scores, probs, bg_ws, sums);
  finalize<<<32, 256, 0, stream>>>(bg_ws, sums, kp, y, aux);
}